// Round 8
// baseline (1010.572 us; speedup 1.0000x reference)
//
#include <hip/hip_runtime.h>
#include <hip/hip_bf16.h>

// Grouped GEMM: E=16 experts, each [2048x1024] @ [1024x4096], fp32 in/out.
// Round 8:
//   Pass 1 (fused): A fp32->bf16 convert + W [K][N]->WT [N][K] bf16 transpose.
//   Pass 2 : NON-persistent 256x256 tile (grid 2048), BK=64, 8 waves (2Mx4N),
//            128 KiB LDS double buffer, involution swizzle (conflict-free),
//            8 phases per 2 k-tiles with ONE-PHASE-AHEAD register pre-reads
//            (counted lgkmcnt(4/8) -- a phase never drains its own reads),
//            counted vmcnt(2/2/2/4), tail-tightened (VMC(0) when stage
//            skipped), XCD-bijective block swizzle.

#define E_NUM 16
#define M_PER_E 2048
#define K_DIM 1024
#define N_DIM 4096

#define A_ELEMS (E_NUM * M_PER_E * K_DIM)
#define W_ELEMS (E_NUM * K_DIM * N_DIM)
#define WS_NEEDED ((size_t)A_ELEMS * 2 + (size_t)W_ELEMS * 2)

typedef float  float4v  __attribute__((ext_vector_type(4)));
typedef float  f32x4    __attribute__((ext_vector_type(4)));
typedef short  bf16x8   __attribute__((ext_vector_type(8)));
typedef unsigned short ushort4v __attribute__((ext_vector_type(4)));
typedef unsigned short ushort8v __attribute__((ext_vector_type(8)));

__device__ __forceinline__ ushort4v cvt4_bf16(float4v f) {
    union { __bf16 h[4]; ushort4v u; } x;
#pragma unroll
    for (int j = 0; j < 4; ++j) x.h[j] = (__bf16)f[j];
    return x.u;
}

// ---------------- Pass 1: fused prepass ----------------
// blocks [0,16384): W transpose (64x64 tiles); blocks [16384,18432): A convert.
__global__ __launch_bounds__(256) void prepass_kernel(
    const float* __restrict__ A, const float* __restrict__ W,
    unsigned short* __restrict__ outA, unsigned short* __restrict__ outW)
{
    __shared__ __align__(16) float T[64 * 64];
    const int b = blockIdx.x;
    const int t = threadIdx.x;

    if (b < 16384) {
        const int nt = b & 63;
        const int kt = (b >> 6) & 15;
        const int e  = b >> 10;
        const float* Wb = W + ((size_t)e * K_DIM + (size_t)kt * 64) * N_DIM + nt * 64;

#pragma unroll
        for (int j = 0; j < 4; ++j) {
            int kl = (t >> 4) + j * 16;
            int n4 = t & 15;
            float4v v = *reinterpret_cast<const float4v*>(Wb + (size_t)kl * N_DIM + n4 * 4);
            int sp = n4 ^ ((kl >> 3) & 7);
            *reinterpret_cast<float4v*>(&T[kl * 64 + sp * 4]) = v;
        }
        __syncthreads();

#pragma unroll
        for (int c = 0; c < 2; ++c) {
            int nl = (t >> 3) + c * 32;
            int kc = t & 7;
            ushort8v v;
#pragma unroll
            for (int j = 0; j < 8; ++j) {
                int kl = kc * 8 + j;
                int sp = (nl >> 2) ^ kc;
                float f = T[kl * 64 + sp * 4 + (nl & 3)];
                union { __bf16 h; unsigned short u; } cv; cv.h = (__bf16)f;
                v[j] = cv.u;
            }
            unsigned short* dst = outW + ((size_t)e * N_DIM + (size_t)nt * 64 + nl) * K_DIM
                                  + (size_t)kt * 64 + kc * 8;
            *reinterpret_cast<ushort8v*>(dst) = v;
        }
    } else {
        const int n8 = A_ELEMS / 8;
        int idx = (b - 16384) * 256 + t;
        int stride = 2048 * 256;
        for (int i = idx; i < n8; i += stride) {
            float4v a = *reinterpret_cast<const float4v*>(A + (size_t)i * 8);
            float4v bb = *reinterpret_cast<const float4v*>(A + (size_t)i * 8 + 4);
            ushort8v v;
            ushort4v va = cvt4_bf16(a), vb = cvt4_bf16(bb);
#pragma unroll
            for (int j = 0; j < 4; ++j) { v[j] = va[j]; v[j + 4] = vb[j]; }
            *reinterpret_cast<ushort8v*>(outA + (size_t)i * 8) = v;
        }
    }
}

// ---------------- Pass 2: 256^2 bf16 GEMM, phase-ahead 8-phase pipeline ------
#define GBM 256
#define GBN 256
#define GBK 64
#define NKT 16   // k-tiles per block

#define BARX()  __builtin_amdgcn_s_barrier()
#define SB0()   __builtin_amdgcn_sched_barrier(0)
#define LGKM(N) asm volatile("s_waitcnt lgkmcnt(" #N ")" ::: "memory")
#define VMC(N)  asm volatile("s_waitcnt vmcnt(" #N ")" ::: "memory")

__global__ __launch_bounds__(512, 2) void gemm_bf16_kernel(
    const unsigned short* __restrict__ A,   // [E*2048][1024] bf16
    const unsigned short* __restrict__ B,   // [E*4096][1024] bf16 (W^T)
    float* __restrict__ C)                  // [E*2048][4096] fp32
{
    // XCD-bijective swizzle over 2048 blocks (2048 % 8 == 0)
    const int bid = blockIdx.x;
    const int swzid = (bid & 7) * (2048 / 8) + (bid >> 3);
    const int e   = swzid >> 7;
    const int rem = swzid & 127;
    const int bm  = rem >> 4;          // 0..7
    const int bn  = rem & 15;          // 0..15

    const int tid  = threadIdx.x;
    const int lane = tid & 63;
    const int wid  = tid >> 6;         // 0..7
    const int wm   = wid >> 2;         // 0..1  (128 rows)
    const int wn   = wid & 3;          // 0..3  (64 cols)
    const int lrow = lane & 15;
    const int kq   = lane >> 4;        // 0..3

    __shared__ __align__(16) unsigned short sA[2][GBM * GBK];
    __shared__ __align__(16) unsigned short sB[2][GBN * GBK];

    const unsigned short* Abase = A + ((size_t)e * M_PER_E + (size_t)bm * GBM) * K_DIM;
    const unsigned short* Bbase = B + ((size_t)e * N_DIM  + (size_t)bn * GBN) * K_DIM;
    float*                Cbase = C + ((size_t)e * M_PER_E + (size_t)bm * GBM) * N_DIM
                                    + (size_t)bn * GBN;

    // Involution swizzle: phys_slot = logical_chunk ^ (row & 7); gload_lds
    // writes linearly, so the global source pre-applies the inverse.
    const int schunk = (lane & 7) ^ ((lane >> 3) & 7);
    const int srow   = lane >> 3;

    // one A quarter (64 rows): 1 gload_lds per thread
    auto STAGE_AQ = [&](int t, int q) {
        const unsigned short* src = Abase + (size_t)(q * 64 + wid * 8 + srow) * K_DIM
                                    + t * GBK + schunk * 8;
        __builtin_amdgcn_global_load_lds(
            (const __attribute__((address_space(1))) void*)src,
            (__attribute__((address_space(3))) void*)&sA[t & 1][(q * 64 + wid * 8) * GBK],
            16, 0, 0);
    };
    // one B half (128 rows): 2 gload_lds per thread
    auto STAGE_BH = [&](int t, int h) {
#pragma unroll
        for (int j2 = 0; j2 < 2; ++j2) {
            int rb = h * 128 + (wid * 2 + j2) * 8;
            const unsigned short* src = Bbase + (size_t)(rb + srow) * K_DIM
                                        + t * GBK + schunk * 8;
            __builtin_amdgcn_global_load_lds(
                (const __attribute__((address_space(1))) void*)src,
                (__attribute__((address_space(3))) void*)&sB[t & 1][rb * GBK],
                16, 0, 0);
        }
    };

    f32x4 acc[8][4];
#pragma unroll
    for (int mf = 0; mf < 8; ++mf)
#pragma unroll
        for (int nf = 0; nf < 4; ++nf) acc[mf][nf] = (f32x4)0.0f;

    bf16x8 afP[4], afQ[4], bfP[4], bfQ[4];

    auto READ_AF = [&](bf16x8* dst, int p, int mh, int s) {   // 4 ds_read_b128
        const int slot = (s * 4 + kq) ^ (lrow & 7);
#pragma unroll
        for (int mf = 0; mf < 4; ++mf) {
            int row = wm * 128 + mh * 64 + mf * 16 + lrow;
            dst[mf] = *reinterpret_cast<const bf16x8*>(&sA[p][row * GBK + slot * 8]);
        }
    };
    auto READ_BF = [&](bf16x8* dst, int p, int s) {           // 4 ds_read_b128
        const int slot = (s * 4 + kq) ^ (lrow & 7);
#pragma unroll
        for (int nf = 0; nf < 4; ++nf) {
            int row = wn * 64 + nf * 16 + lrow;
            dst[nf] = *reinterpret_cast<const bf16x8*>(&sB[p][row * GBK + slot * 8]);
        }
    };
    auto MMQ = [&](const bf16x8* af, const bf16x8* bf, int mh) {  // 16 MFMA
        __builtin_amdgcn_s_setprio(1);
#pragma unroll
        for (int nf = 0; nf < 4; ++nf)
#pragma unroll
            for (int mf = 0; mf < 4; ++mf)
                acc[mh * 4 + mf][nf] = __builtin_amdgcn_mfma_f32_16x16x32_bf16(
                    af[mf], bf[nf], acc[mh * 4 + mf][nf], 0, 0, 0);
        __builtin_amdgcn_s_setprio(0);
    };

    // ---- prologue: tile0 loads are the OLDEST 8 per wave, then B(1):4.
    STAGE_AQ(0, 0); STAGE_AQ(0, 1); STAGE_AQ(0, 2); STAGE_AQ(0, 3);  // 4/wave
    STAGE_BH(0, 0); STAGE_BH(0, 1);                                  // 4/wave
    STAGE_BH(1, 0); STAGE_BH(1, 1);                                  // 4/wave
    VMC(4);          // retire oldest 8 = A(0)+B(0); B(1):4 may fly
    BARX();
    READ_AF(afP, 0, 0, 0);
    READ_BF(bfP, 0, 0);

#pragma unroll 1
    for (int i = 0; i < NKT / 2; ++i) {
        const int g = 2 * i;   // even tile u -> buf0; v = g+1 -> buf1
        // ---- P1: MMQ(u,mh0,s0); pre-read af(u,mh1,s0)
        READ_AF(afQ, 0, 1, 0);
        STAGE_AQ(g + 1, 0); STAGE_AQ(g + 1, 2);
        BARX(); LGKM(4); SB0();
        MMQ(afP, bfP, 0);
        BARX();
        // ---- P2: MMQ(u,mh1,s0); pre-read af(u,mh0,s1)+bf(u,s1)
        READ_AF(afP, 0, 0, 1); READ_BF(bfQ, 0, 1);
        STAGE_AQ(g + 1, 1); STAGE_AQ(g + 1, 3);
        BARX(); LGKM(8); SB0();
        MMQ(afQ, bfP, 1);
        BARX();
        // ---- P3: MMQ(u,mh0,s1); pre-read af(u,mh1,s1)
        READ_AF(afQ, 0, 1, 1);
        BARX(); LGKM(4); SB0();
        MMQ(afP, bfQ, 0);
        VMC(2);   // retire prevH B(v):4 + A(v)q0,q2 -> P4's mh0 reads safe
        BARX();
        // ---- P4: MMQ(u,mh1,s1); pre-read af(v,mh0,s0)+bf(v,s0)
        READ_AF(afP, 1, 0, 0); READ_BF(bfP, 1, 0);
        if (g + 2 < NKT) STAGE_BH(g + 2, 0);
        BARX(); LGKM(8); SB0();
        MMQ(afQ, bfQ, 1);
        if (g + 2 < NKT) { VMC(2); } else { VMC(0); }  // A(v)q1,q3 landed
        BARX();
        // ---- P5: MMQ(v,mh0,s0); pre-read af(v,mh1,s0)
        READ_AF(afQ, 1, 1, 0);
        if (g + 2 < NKT) STAGE_BH(g + 2, 1);
        BARX(); LGKM(4); SB0();
        MMQ(afP, bfP, 0);
        BARX();
        // ---- P6: MMQ(v,mh1,s0); pre-read af(v,mh0,s1)+bf(v,s1)
        READ_AF(afP, 1, 0, 1); READ_BF(bfQ, 1, 1);
        if (g + 2 < NKT) { STAGE_AQ(g + 2, 0); STAGE_AQ(g + 2, 2); }
        BARX(); LGKM(8); SB0();
        MMQ(afQ, bfP, 1);
        BARX();
        // ---- P7: MMQ(v,mh0,s1); pre-read af(v,mh1,s1)
        READ_AF(afQ, 1, 1, 1);
        if (g + 2 < NKT) { STAGE_AQ(g + 2, 1); STAGE_AQ(g + 2, 3); }
        BARX(); LGKM(4); SB0();
        MMQ(afP, bfQ, 0);
        VMC(2);   // retire B(u+2) h0,h1 + A(u+2) q0,q2 -> P8 pre-reads safe
        BARX();
        // ---- P8: MMQ(v,mh1,s1); pre-read af(u+2,mh0,s0)+bf(u+2,s0)
        if (g + 2 < NKT) { READ_AF(afP, 0, 0, 0); READ_BF(bfP, 0, 0); }
        if (g + 3 < NKT) { STAGE_BH(g + 3, 0); STAGE_BH(g + 3, 1); }
        BARX();
        if (g + 2 < NKT) { LGKM(8); } else { LGKM(0); }
        SB0();
        MMQ(afQ, bfQ, 1);
        VMC(4);   // retire A(u+2) q1,q3; B(u+2+1):4 may fly
        BARX();
    }

    // epilogue: C/D layout col=lane&15, row=(lane>>4)*4+j  [m89]
#pragma unroll
    for (int mf = 0; mf < 8; ++mf) {
#pragma unroll
        for (int nf = 0; nf < 4; ++nf) {
#pragma unroll
            for (int j = 0; j < 4; ++j) {
                int row = wm * 128 + mf * 16 + kq * 4 + j;
                int col = wn * 64 + nf * 16 + lrow;
                Cbase[(size_t)row * N_DIM + col] = acc[mf][nf][j];
            }
        }
    }
}

// ---------------- Fallback: round-1 fused kernel ----------------
#define BM 128
#define BN 128
#define BK 64
#define KT (K_DIM / BK)

__device__ __forceinline__ int swz_f(int row, int kelem) {
    return kelem ^ (((row ^ (row >> 3)) & 7) << 3);
}

__global__ __launch_bounds__(256) void grouped_gemm_fused_kernel(
    const float* __restrict__ A, const float* __restrict__ W, float* __restrict__ C)
{
    const int bn = blockIdx.x;
    const int bm = blockIdx.y;
    const int e  = blockIdx.z;
    const int tid  = threadIdx.x;
    const int lane = tid & 63;
    const int wid  = tid >> 6;
    const int wr   = wid >> 1;
    const int wc   = wid & 1;

    __shared__ __align__(16) unsigned short fA[BM * BK];
    __shared__ __align__(16) unsigned short fB[BN * BK];

    const float* Abase = A + ((size_t)e * M_PER_E + (size_t)bm * BM) * K_DIM;
    const float* Wbase = W + (size_t)e * K_DIM * N_DIM + (size_t)bn * BN;
    float*       Cbase = C + ((size_t)e * M_PER_E + (size_t)bm * BM) * N_DIM + (size_t)bn * BN;

    const int arow  = tid >> 4;
    const int acol4 = (tid & 15) * 4;
    const int bkq   = tid >> 4;
    const int bnq   = tid & 15;

    f32x4 acc[4][4];
#pragma unroll
    for (int m = 0; m < 4; ++m)
#pragma unroll
        for (int n = 0; n < 4; ++n) acc[m][n] = (f32x4)0.0f;

    float4v ra[8], rb[8];

    auto LOADT = [&](int kt) {
        const float* ap = Abase + (size_t)arow * K_DIM + kt * BK + acol4;
#pragma unroll
        for (int i = 0; i < 8; ++i)
            ra[i] = *reinterpret_cast<const float4v*>(ap + (size_t)i * 16 * K_DIM);
        const float* bp = Wbase + (size_t)(kt * BK + bkq * 4) * N_DIM + bnq * 4;
#pragma unroll
        for (int i = 0; i < 2; ++i)
#pragma unroll
            for (int r = 0; r < 4; ++r)
                rb[i * 4 + r] = *reinterpret_cast<const float4v*>(bp + (size_t)r * N_DIM + i * 64);
    };

    auto STORET = [&]() {
#pragma unroll
        for (int i = 0; i < 8; ++i) {
            int row = arow + i * 16;
            ushort4v v = cvt4_bf16(ra[i]);
            *reinterpret_cast<ushort4v*>(&fA[row * BK + swz_f(row, acol4)]) = v;
        }
#pragma unroll
        for (int i = 0; i < 2; ++i) {
#pragma unroll
            for (int j = 0; j < 4; ++j) {
                int n = (bnq + i * 16) * 4 + j;
                float4v col;
                col[0] = rb[i * 4 + 0][j];
                col[1] = rb[i * 4 + 1][j];
                col[2] = rb[i * 4 + 2][j];
                col[3] = rb[i * 4 + 3][j];
                ushort4v v = cvt4_bf16(col);
                *reinterpret_cast<ushort4v*>(&fB[n * BK + swz_f(n, bkq * 4)]) = v;
            }
        }
    };

    auto COMPUTE = [&]() {
#pragma unroll
        for (int s = 0; s < 2; ++s) {
            bf16x8 af[4], bfr[4];
            const int ke = s * 32 + (lane >> 4) * 8;
#pragma unroll
            for (int m = 0; m < 4; ++m) {
                int row = wr * 64 + m * 16 + (lane & 15);
                af[m] = *reinterpret_cast<const bf16x8*>(&fA[row * BK + swz_f(row, ke)]);
            }
#pragma unroll
            for (int n = 0; n < 4; ++n) {
                int row = wc * 64 + n * 16 + (lane & 15);
                bfr[n] = *reinterpret_cast<const bf16x8*>(&fB[row * BK + swz_f(row, ke)]);
            }
#pragma unroll
            for (int m = 0; m < 4; ++m)
#pragma unroll
                for (int n = 0; n < 4; ++n)
                    acc[m][n] = __builtin_amdgcn_mfma_f32_16x16x32_bf16(
                        af[m], bfr[n], acc[m][n], 0, 0, 0);
        }
    };

    LOADT(0);
    STORET();
    __syncthreads();
    for (int kt = 0; kt < KT; ++kt) {
        if (kt + 1 < KT) LOADT(kt + 1);
        COMPUTE();
        __syncthreads();
        if (kt + 1 < KT) STORET();
        __syncthreads();
    }

#pragma unroll
    for (int m = 0; m < 4; ++m)
#pragma unroll
        for (int n = 0; n < 4; ++n)
#pragma unroll
            for (int j = 0; j < 4; ++j) {
                int row = wr * 64 + m * 16 + (lane >> 4) * 4 + j;
                int col = wc * 64 + n * 16 + (lane & 15);
                Cbase[(size_t)row * N_DIM + col] = acc[m][n][j];
            }
}

extern "C" void kernel_launch(void* const* d_in, const int* in_sizes, int n_in,
                              void* d_out, int out_size, void* d_ws, size_t ws_size,
                              hipStream_t stream) {
    const float* A = (const float*)d_in[0];
    // d_in[1] = expert_size (static 2048 each) — unused
    const float* W = (const float*)d_in[2];
    float* out = (float*)d_out;

    if (ws_size >= WS_NEEDED) {
        unsigned short* wsA = (unsigned short*)d_ws;
        unsigned short* wsW = wsA + (size_t)A_ELEMS;

        hipLaunchKernelGGL(prepass_kernel, dim3(18432), dim3(256), 0, stream,
                           A, W, wsA, wsW);
        hipLaunchKernelGGL(gemm_bf16_kernel, dim3(2048), dim3(512), 0, stream,
                           wsA, wsW, out);
    } else {
        dim3 grid(N_DIM / BN, M_PER_E / BM, E_NUM);
        hipLaunchKernelGGL(grouped_gemm_fused_kernel, grid, dim3(256), 0, stream,
                           A, W, out);
    }
}

// Round 9
// 578.572 us; speedup vs baseline: 1.7467x; 1.7467x over previous
//
#include <hip/hip_runtime.h>
#include <hip/hip_bf16.h>

// Grouped GEMM: E=16 experts, each [2048x1024] @ [1024x4096], fp32 in/out.
// Round 9:
//   Pass 1 (fused): A fp32->bf16 convert + W [K][N]->WT [N][K] bf16 transpose.
//   Pass 2 : m97-structure GEMM (verified 912 TF @ m103): 128x128 tile, BK=32,
//            4 waves (2x2, 64x64 each), 32 KB LDS double buffer -> multi-block
//            per CU (wave-level overlap hides barrier drain, m114), simple
//            2-barrier loop, gload_lds w=16 with CONFLICT-FREE involution
//            swizzle (read slot = kq ^ ((row>>1)&3); source (l&3)^((l>>3)&3);
//            proven 0 conflicts in R7), XCD-bijective block swizzle.
//   This is R2's kernel with its 4-way-conflict swizzle bug fixed (R2 ran
//   480us with 3.4e7 conflict-cycles; m136 says 4-way = 1.58x => ~304us).

#define E_NUM 16
#define M_PER_E 2048
#define K_DIM 1024
#define N_DIM 4096

#define A_ELEMS (E_NUM * M_PER_E * K_DIM)
#define W_ELEMS (E_NUM * K_DIM * N_DIM)
#define WS_NEEDED ((size_t)A_ELEMS * 2 + (size_t)W_ELEMS * 2)

typedef float  float4v  __attribute__((ext_vector_type(4)));
typedef float  f32x4    __attribute__((ext_vector_type(4)));
typedef short  bf16x8   __attribute__((ext_vector_type(8)));
typedef unsigned short ushort4v __attribute__((ext_vector_type(4)));
typedef unsigned short ushort8v __attribute__((ext_vector_type(8)));

__device__ __forceinline__ ushort4v cvt4_bf16(float4v f) {
    union { __bf16 h[4]; ushort4v u; } x;
#pragma unroll
    for (int j = 0; j < 4; ++j) x.h[j] = (__bf16)f[j];
    return x.u;
}

// ---------------- Pass 1: fused prepass ----------------
// blocks [0,16384): W transpose (64x64 tiles); blocks [16384,18432): A convert.
__global__ __launch_bounds__(256) void prepass_kernel(
    const float* __restrict__ A, const float* __restrict__ W,
    unsigned short* __restrict__ outA, unsigned short* __restrict__ outW)
{
    __shared__ __align__(16) float T[64 * 64];
    const int b = blockIdx.x;
    const int t = threadIdx.x;

    if (b < 16384) {
        const int nt = b & 63;
        const int kt = (b >> 6) & 15;
        const int e  = b >> 10;
        const float* Wb = W + ((size_t)e * K_DIM + (size_t)kt * 64) * N_DIM + nt * 64;

#pragma unroll
        for (int j = 0; j < 4; ++j) {
            int kl = (t >> 4) + j * 16;
            int n4 = t & 15;
            float4v v = *reinterpret_cast<const float4v*>(Wb + (size_t)kl * N_DIM + n4 * 4);
            int sp = n4 ^ ((kl >> 3) & 7);
            *reinterpret_cast<float4v*>(&T[kl * 64 + sp * 4]) = v;
        }
        __syncthreads();

#pragma unroll
        for (int c = 0; c < 2; ++c) {
            int nl = (t >> 3) + c * 32;
            int kc = t & 7;
            ushort8v v;
#pragma unroll
            for (int j = 0; j < 8; ++j) {
                int kl = kc * 8 + j;
                int sp = (nl >> 2) ^ kc;
                float f = T[kl * 64 + sp * 4 + (nl & 3)];
                union { __bf16 h; unsigned short u; } cv; cv.h = (__bf16)f;
                v[j] = cv.u;
            }
            unsigned short* dst = outW + ((size_t)e * N_DIM + (size_t)nt * 64 + nl) * K_DIM
                                  + (size_t)kt * 64 + kc * 8;
            *reinterpret_cast<ushort8v*>(dst) = v;
        }
    } else {
        const int n8 = A_ELEMS / 8;
        int idx = (b - 16384) * 256 + t;
        int stride = 2048 * 256;
        for (int i = idx; i < n8; i += stride) {
            float4v a = *reinterpret_cast<const float4v*>(A + (size_t)i * 8);
            float4v bb = *reinterpret_cast<const float4v*>(A + (size_t)i * 8 + 4);
            ushort8v v;
            ushort4v va = cvt4_bf16(a), vb = cvt4_bf16(bb);
#pragma unroll
            for (int j = 0; j < 4; ++j) { v[j] = va[j]; v[j + 4] = vb[j]; }
            *reinterpret_cast<ushort8v*>(outA + (size_t)i * 8) = v;
        }
    }
}

// ---------------- Pass 2: bf16 GEMM (m97 structure, conflict-free) ----------
#define GBM 128
#define GBN 128
#define GBK 32
#define GKT (K_DIM / GBK)   // 32

__global__ __launch_bounds__(256) void gemm_bf16_kernel(
    const unsigned short* __restrict__ A,   // [E*2048][1024] bf16
    const unsigned short* __restrict__ B,   // [E*4096][1024] bf16 (W^T)
    float* __restrict__ C)                  // [E*2048][4096] fp32
{
    // XCD-bijective swizzle over 8192 blocks (8192 % 8 == 0)
    const int bid = blockIdx.x;
    const int swzid = (bid & 7) * (8192 / 8) + (bid >> 3);
    const int e  = swzid >> 9;          // /512
    const int rem = swzid & 511;
    const int bm = rem >> 5;            // 0..15
    const int bn = rem & 31;            // 0..31

    const int tid  = threadIdx.x;
    const int lane = tid & 63;
    const int wid  = tid >> 6;
    const int wr   = wid >> 1;
    const int wc   = wid & 1;
    const int lrow = lane & 15;
    const int kq   = lane >> 4;         // logical 16B k-chunk 0..3

    __shared__ __align__(16) unsigned short sA[2][GBM * GBK];  // 8 KB each
    __shared__ __align__(16) unsigned short sB[2][GBN * GBK];  // 8 KB each

    const unsigned short* Abase = A + ((size_t)e * M_PER_E + (size_t)bm * GBM) * K_DIM;
    const unsigned short* Bbase = B + ((size_t)e * N_DIM  + (size_t)bn * GBN) * K_DIM;
    float*                Cbase = C + ((size_t)e * M_PER_E + (size_t)bm * GBM) * N_DIM
                                    + (size_t)bn * GBN;

    // Conflict-free involution swizzle (proven 0 conflicts, R7):
    //   phys_slot = logical_chunk ^ ((row>>1)&3)   [row = 64B = 4 x 16B slots]
    // gload_lds writes linearly (lane l -> row l>>2, slot l&3; row base mult.
    // of 16), so the global source pre-applies the inverse:
    //   logical chunk = (l&3) ^ ((l>>3)&3)
    const int srow   = lane >> 2;
    const int schunk = (lane & 3) ^ ((lane >> 3) & 3);

    auto STAGE = [&](int buf, int kt) {
#pragma unroll
        for (int i = 0; i < 2; ++i) {
            int rbase = (wid * 2 + i) * 16;
            const unsigned short* ga = Abase + (size_t)(rbase + srow) * K_DIM
                                       + kt * GBK + schunk * 8;
            __builtin_amdgcn_global_load_lds(
                (const __attribute__((address_space(1))) void*)ga,
                (__attribute__((address_space(3))) void*)&sA[buf][rbase * GBK],
                16, 0, 0);
            const unsigned short* gb = Bbase + (size_t)(rbase + srow) * K_DIM
                                       + kt * GBK + schunk * 8;
            __builtin_amdgcn_global_load_lds(
                (const __attribute__((address_space(1))) void*)gb,
                (__attribute__((address_space(3))) void*)&sB[buf][rbase * GBK],
                16, 0, 0);
        }
    };

    f32x4 acc[4][4];
#pragma unroll
    for (int m = 0; m < 4; ++m)
#pragma unroll
        for (int n = 0; n < 4; ++n) acc[m][n] = (f32x4)0.0f;

    auto COMPUTE = [&](int buf) {
        bf16x8 af[4], bfr[4];
#pragma unroll
        for (int m = 0; m < 4; ++m) {
            int row = wr * 64 + m * 16 + lrow;
            int ps = kq ^ ((row >> 1) & 3);
            af[m] = *reinterpret_cast<const bf16x8*>(&sA[buf][row * GBK + ps * 8]);
        }
#pragma unroll
        for (int n = 0; n < 4; ++n) {
            int row = wc * 64 + n * 16 + lrow;
            int ps = kq ^ ((row >> 1) & 3);
            bfr[n] = *reinterpret_cast<const bf16x8*>(&sB[buf][row * GBK + ps * 8]);
        }
#pragma unroll
        for (int m = 0; m < 4; ++m)
#pragma unroll
            for (int n = 0; n < 4; ++n)
                acc[m][n] = __builtin_amdgcn_mfma_f32_16x16x32_bf16(
                    af[m], bfr[n], acc[m][n], 0, 0, 0);
    };

    STAGE(0, 0);
    __syncthreads();
    int buf = 0;
#pragma unroll 1
    for (int kt = 0; kt < GKT - 1; ++kt) {
        STAGE(buf ^ 1, kt + 1);   // loads stay in flight under MFMA
        COMPUTE(buf);
        __syncthreads();          // drains vmcnt + lgkm, flips buffer safely
        buf ^= 1;
    }
    COMPUTE(buf);

    // epilogue: C/D layout col=lane&15, row=(lane>>4)*4+j  [m89]
#pragma unroll
    for (int m = 0; m < 4; ++m) {
#pragma unroll
        for (int n = 0; n < 4; ++n) {
#pragma unroll
            for (int j = 0; j < 4; ++j) {
                int row = wr * 64 + m * 16 + kq * 4 + j;
                int col = wc * 64 + n * 16 + lrow;
                Cbase[(size_t)row * N_DIM + col] = acc[m][n][j];
            }
        }
    }
}

// ---------------- Fallback: round-1 fused kernel ----------------
#define BM 128
#define BN 128
#define BK 64
#define KT (K_DIM / BK)

__device__ __forceinline__ int swz_f(int row, int kelem) {
    return kelem ^ (((row ^ (row >> 3)) & 7) << 3);
}

__global__ __launch_bounds__(256) void grouped_gemm_fused_kernel(
    const float* __restrict__ A, const float* __restrict__ W, float* __restrict__ C)
{
    const int bn = blockIdx.x;
    const int bm = blockIdx.y;
    const int e  = blockIdx.z;
    const int tid  = threadIdx.x;
    const int lane = tid & 63;
    const int wid  = tid >> 6;
    const int wr   = wid >> 1;
    const int wc   = wid & 1;

    __shared__ __align__(16) unsigned short fA[BM * BK];
    __shared__ __align__(16) unsigned short fB[BN * BK];

    const float* Abase = A + ((size_t)e * M_PER_E + (size_t)bm * BM) * K_DIM;
    const float* Wbase = W + (size_t)e * K_DIM * N_DIM + (size_t)bn * BN;
    float*       Cbase = C + ((size_t)e * M_PER_E + (size_t)bm * BM) * N_DIM + (size_t)bn * BN;

    const int arow  = tid >> 4;
    const int acol4 = (tid & 15) * 4;
    const int bkq   = tid >> 4;
    const int bnq   = tid & 15;

    f32x4 acc[4][4];
#pragma unroll
    for (int m = 0; m < 4; ++m)
#pragma unroll
        for (int n = 0; n < 4; ++n) acc[m][n] = (f32x4)0.0f;

    float4v ra[8], rb[8];

    auto LOADT = [&](int kt) {
        const float* ap = Abase + (size_t)arow * K_DIM + kt * BK + acol4;
#pragma unroll
        for (int i = 0; i < 8; ++i)
            ra[i] = *reinterpret_cast<const float4v*>(ap + (size_t)i * 16 * K_DIM);
        const float* bp = Wbase + (size_t)(kt * BK + bkq * 4) * N_DIM + bnq * 4;
#pragma unroll
        for (int i = 0; i < 2; ++i)
#pragma unroll
            for (int r = 0; r < 4; ++r)
                rb[i * 4 + r] = *reinterpret_cast<const float4v*>(bp + (size_t)r * N_DIM + i * 64);
    };

    auto STORET = [&]() {
#pragma unroll
        for (int i = 0; i < 8; ++i) {
            int row = arow + i * 16;
            ushort4v v = cvt4_bf16(ra[i]);
            *reinterpret_cast<ushort4v*>(&fA[row * BK + swz_f(row, acol4)]) = v;
        }
#pragma unroll
        for (int i = 0; i < 2; ++i) {
#pragma unroll
            for (int j = 0; j < 4; ++j) {
                int n = (bnq + i * 16) * 4 + j;
                float4v col;
                col[0] = rb[i * 4 + 0][j];
                col[1] = rb[i * 4 + 1][j];
                col[2] = rb[i * 4 + 2][j];
                col[3] = rb[i * 4 + 3][j];
                ushort4v v = cvt4_bf16(col);
                *reinterpret_cast<ushort4v*>(&fB[n * BK + swz_f(n, bkq * 4)]) = v;
            }
        }
    };

    auto COMPUTE = [&]() {
#pragma unroll
        for (int s = 0; s < 2; ++s) {
            bf16x8 af[4], bfr[4];
            const int ke = s * 32 + (lane >> 4) * 8;
#pragma unroll
            for (int m = 0; m < 4; ++m) {
                int row = wr * 64 + m * 16 + (lane & 15);
                af[m] = *reinterpret_cast<const bf16x8*>(&fA[row * BK + swz_f(row, ke)]);
            }
#pragma unroll
            for (int n = 0; n < 4; ++n) {
                int row = wc * 64 + n * 16 + (lane & 15);
                bfr[n] = *reinterpret_cast<const bf16x8*>(&fB[row * BK + swz_f(row, ke)]);
            }
#pragma unroll
            for (int m = 0; m < 4; ++m)
#pragma unroll
                for (int n = 0; n < 4; ++n)
                    acc[m][n] = __builtin_amdgcn_mfma_f32_16x16x32_bf16(
                        af[m], bfr[n], acc[m][n], 0, 0, 0);
        }
    };

    LOADT(0);
    STORET();
    __syncthreads();
    for (int kt = 0; kt < KT; ++kt) {
        if (kt + 1 < KT) LOADT(kt + 1);
        COMPUTE();
        __syncthreads();
        if (kt + 1 < KT) STORET();
        __syncthreads();
    }

#pragma unroll
    for (int m = 0; m < 4; ++m)
#pragma unroll
        for (int n = 0; n < 4; ++n)
#pragma unroll
            for (int j = 0; j < 4; ++j) {
                int row = wr * 64 + m * 16 + (lane >> 4) * 4 + j;
                int col = wc * 64 + n * 16 + (lane & 15);
                Cbase[(size_t)row * N_DIM + col] = acc[m][n][j];
            }
}

extern "C" void kernel_launch(void* const* d_in, const int* in_sizes, int n_in,
                              void* d_out, int out_size, void* d_ws, size_t ws_size,
                              hipStream_t stream) {
    const float* A = (const float*)d_in[0];
    // d_in[1] = expert_size (static 2048 each) — unused
    const float* W = (const float*)d_in[2];
    float* out = (float*)d_out;

    if (ws_size >= WS_NEEDED) {
        unsigned short* wsA = (unsigned short*)d_ws;
        unsigned short* wsW = wsA + (size_t)A_ELEMS;

        hipLaunchKernelGGL(prepass_kernel, dim3(18432), dim3(256), 0, stream,
                           A, W, wsA, wsW);
        hipLaunchKernelGGL(gemm_bf16_kernel, dim3(8192), dim3(256), 0, stream,
                           wsA, wsW, out);
    } else {
        dim3 grid(N_DIM / BN, M_PER_E / BM, E_NUM);
        hipLaunchKernelGGL(grouped_gemm_fused_kernel, grid, dim3(256), 0, stream,
                           A, W, out);
    }
}

// Round 10
// 463.842 us; speedup vs baseline: 2.1787x; 1.2473x over previous
//
#include <hip/hip_runtime.h>
#include <hip/hip_bf16.h>

// Grouped GEMM: E=16 experts, each [2048x1024] @ [1024x4096], fp32 in/out.
// Round 10 = Round 5 restore (best-known: 462.8 us total, GEMM 350 us):
//   Pass 1a: A fp32 -> bf16 (coalesced)
//   Pass 1b: W [K][N] fp32 -> WT [N][K] bf16 (LDS-tiled transpose)
//   Pass 2 : 256x256 tile, BK=64, 8 waves (2Mx4N), 128 KiB LDS double buffer,
//            full 8-phase schedule (T3+T4): per phase {quadrant ds_reads ||
//            1 half-tile gload_lds -> barrier -> lgkm(0) -> setprio ->
//            16 MFMA -> barrier}, counted vmcnt(4) at P4/P8 only,
//            involution LDS swizzle (conflict-free), XCD-bijective swizzle.
// Post-mortem history: R4 reg-tile neutral; R6/R8 counted-waitcnt restructures
// collapse to HBM-locality-bound; R7 small-tile occupancy -> LDS-bound;
// R9 conflict-fix -> conflicts weren't critical path. This schedule is the
// family optimum for this shape (m248: 848 TF cap on grouped 256^2 K=1024).

#define E_NUM 16
#define M_PER_E 2048
#define K_DIM 1024
#define N_DIM 4096

#define A_ELEMS (E_NUM * M_PER_E * K_DIM)
#define W_ELEMS (E_NUM * K_DIM * N_DIM)
#define WS_NEEDED ((size_t)A_ELEMS * 2 + (size_t)W_ELEMS * 2)

typedef float  float4v  __attribute__((ext_vector_type(4)));
typedef float  f32x4    __attribute__((ext_vector_type(4)));
typedef short  bf16x8   __attribute__((ext_vector_type(8)));
typedef unsigned short ushort4v __attribute__((ext_vector_type(4)));
typedef unsigned short ushort8v __attribute__((ext_vector_type(8)));

__device__ __forceinline__ ushort4v cvt4_bf16(float4v f) {
    union { __bf16 h[4]; ushort4v u; } x;
#pragma unroll
    for (int j = 0; j < 4; ++j) x.h[j] = (__bf16)f[j];
    return x.u;
}

// ---------------- Pass 1a: A fp32 -> bf16 ----------------
__global__ __launch_bounds__(256) void convertA_kernel(
    const float* __restrict__ A, unsigned short* __restrict__ out, int n8)
{
    int idx = blockIdx.x * 256 + threadIdx.x;
    int stride = gridDim.x * 256;
    for (int i = idx; i < n8; i += stride) {
        float4v a = *reinterpret_cast<const float4v*>(A + (size_t)i * 8);
        float4v b = *reinterpret_cast<const float4v*>(A + (size_t)i * 8 + 4);
        ushort8v v;
        ushort4v va = cvt4_bf16(a), vb = cvt4_bf16(b);
#pragma unroll
        for (int j = 0; j < 4; ++j) { v[j] = va[j]; v[j + 4] = vb[j]; }
        *reinterpret_cast<ushort8v*>(out + (size_t)i * 8) = v;
    }
}

// ---------------- Pass 1b: W [E][K][N] fp32 -> WT [E][N][K] bf16 ----------------
__global__ __launch_bounds__(256) void transposeW_kernel(
    const float* __restrict__ W, unsigned short* __restrict__ WT)
{
    const int nt = blockIdx.x;   // 0..63  (N tiles)
    const int kt = blockIdx.y;   // 0..15  (K tiles)
    const int e  = blockIdx.z;   // 0..15
    const int t  = threadIdx.x;

    __shared__ __align__(16) float T[64 * 64];

    const float* Wb = W + ((size_t)e * K_DIM + (size_t)kt * 64) * N_DIM + nt * 64;

#pragma unroll
    for (int j = 0; j < 4; ++j) {
        int kl = (t >> 4) + j * 16;
        int n4 = t & 15;
        float4v v = *reinterpret_cast<const float4v*>(Wb + (size_t)kl * N_DIM + n4 * 4);
        int sp = n4 ^ ((kl >> 3) & 7);
        *reinterpret_cast<float4v*>(&T[kl * 64 + sp * 4]) = v;
    }
    __syncthreads();

#pragma unroll
    for (int c = 0; c < 2; ++c) {
        int nl = (t >> 3) + c * 32;
        int kc = t & 7;
        ushort8v v;
#pragma unroll
        for (int j = 0; j < 8; ++j) {
            int kl = kc * 8 + j;
            int sp = (nl >> 2) ^ kc;           // (kl>>3)&7 == kc here
            float f = T[kl * 64 + sp * 4 + (nl & 3)];
            union { __bf16 h; unsigned short u; } cv; cv.h = (__bf16)f;
            v[j] = cv.u;
        }
        unsigned short* dst = WT + ((size_t)e * N_DIM + (size_t)nt * 64 + nl) * K_DIM
                              + (size_t)kt * 64 + kc * 8;
        *reinterpret_cast<ushort8v*>(dst) = v;
    }
}

// ---------------- Pass 2: 256^2 bf16 GEMM, 8-phase pipeline ------------------
#define GBM 256
#define GBN 256
#define GBK 64
#define GKT (K_DIM / GBK)   // 16 K-tiles, 8 iters of 2

#define BAR()   __builtin_amdgcn_s_barrier()
#define LGKM0() asm volatile("s_waitcnt lgkmcnt(0)" ::: "memory")

__global__ __launch_bounds__(512, 2) void gemm_bf16_kernel(
    const unsigned short* __restrict__ A,   // [E*2048][1024] bf16
    const unsigned short* __restrict__ B,   // [E*4096][1024] bf16 (W^T)
    float* __restrict__ C)                  // [E*2048][4096] fp32
{
    // XCD-bijective swizzle over 2048 blocks (2048 % 8 == 0)
    const int bid = blockIdx.x;
    const int swzid = (bid & 7) * (2048 / 8) + (bid >> 3);
    const int e   = swzid >> 7;        // 128 tiles/expert
    const int rem = swzid & 127;
    const int bm  = rem >> 4;          // 0..7
    const int bn  = rem & 15;          // 0..15

    const int tid  = threadIdx.x;
    const int lane = tid & 63;
    const int wid  = tid >> 6;         // 0..7
    const int wm   = wid >> 2;         // 0..1  (128 rows)
    const int wn   = wid & 3;          // 0..3  (64 cols)
    const int lrow = lane & 15;
    const int kq   = lane >> 4;        // 0..3

    // 128 KiB: 2 bufs x (A 32KB + B 32KB); halves = 128 rows each
    __shared__ __align__(16) unsigned short sA[2][GBM * GBK];
    __shared__ __align__(16) unsigned short sB[2][GBN * GBK];

    const unsigned short* Abase = A + ((size_t)e * M_PER_E + (size_t)bm * GBM) * K_DIM;
    const unsigned short* Bbase = B + ((size_t)e * N_DIM  + (size_t)bn * GBN) * K_DIM;
    float*                Cbase = C + ((size_t)e * M_PER_E + (size_t)bm * GBM) * N_DIM
                                    + (size_t)bn * GBN;

    // Involution swizzle: LDS row = 128B = 8 slots of 16B.
    // phys_slot = logical_chunk ^ (row & 7); gload_lds writes linearly, so the
    // global source pre-applies the inverse.
    const int schunk = (lane & 7) ^ ((lane >> 3) & 7);
    const int srow   = lane >> 3;

    // stage one half-tile (128 rows x 64 k) of A or B: 2 gload_lds per thread
    auto STAGE_A = [&](int t, int h) {
        const unsigned short* g = Abase + (size_t)t * GBK + schunk * 8;
#pragma unroll
        for (int j = 0; j < 2; ++j) {
            const int rb = h * 128 + (wid * 2 + j) * 8;
            __builtin_amdgcn_global_load_lds(
                (const __attribute__((address_space(1))) void*)(g + (size_t)(rb + srow) * K_DIM),
                (__attribute__((address_space(3))) void*)&sA[t & 1][rb * GBK], 16, 0, 0);
        }
    };
    auto STAGE_B = [&](int t, int h) {
        const unsigned short* g = Bbase + (size_t)t * GBK + schunk * 8;
#pragma unroll
        for (int j = 0; j < 2; ++j) {
            const int rb = h * 128 + (wid * 2 + j) * 8;
            __builtin_amdgcn_global_load_lds(
                (const __attribute__((address_space(1))) void*)(g + (size_t)(rb + srow) * K_DIM),
                (__attribute__((address_space(3))) void*)&sB[t & 1][rb * GBK], 16, 0, 0);
        }
    };

    f32x4 acc[8][4];
#pragma unroll
    for (int mf = 0; mf < 8; ++mf)
#pragma unroll
        for (int nf = 0; nf < 4; ++nf) acc[mf][nf] = (f32x4)0.0f;

    bf16x8 af[4][2];   // current A quadrant (4 m-frags x 2 k-slices)
    bf16x8 bf[4][2];   // full B panel (4 n-frags x 2 k-slices)

    auto READ_A = [&](int p, int mh) {   // af <- A-half quadrant mh
#pragma unroll
        for (int s = 0; s < 2; ++s) {
            const int slot = (s * 4 + kq) ^ (lrow & 7);
#pragma unroll
            for (int mf = 0; mf < 4; ++mf) {
                int row = wm * 128 + mh * 64 + mf * 16 + lrow;
                af[mf][s] = *reinterpret_cast<const bf16x8*>(&sA[p][row * GBK + slot * 8]);
            }
        }
    };
    auto READ_B = [&](int p, int bh) {   // bf[bh*2..+1]
#pragma unroll
        for (int s = 0; s < 2; ++s) {
            const int slot = (s * 4 + kq) ^ (lrow & 7);
#pragma unroll
            for (int nf = 0; nf < 2; ++nf) {
                int row = wn * 64 + (bh * 2 + nf) * 16 + lrow;
                bf[bh * 2 + nf][s] = *reinterpret_cast<const bf16x8*>(&sB[p][row * GBK + slot * 8]);
            }
        }
    };

    auto MMQ = [&](int mh, int nh) {     // 16 MFMA, one C-quadrant slice
        __builtin_amdgcn_s_setprio(1);
#pragma unroll
        for (int s = 0; s < 2; ++s)
#pragma unroll
            for (int nf = nh * 2; nf < nh * 2 + 2; ++nf)
#pragma unroll
                for (int mf = 0; mf < 4; ++mf)
                    acc[mh * 4 + mf][nf] = __builtin_amdgcn_mfma_f32_16x16x32_bf16(
                        af[mf][s], bf[nf][s], acc[mh * 4 + mf][nf], 0, 0, 0);
        __builtin_amdgcn_s_setprio(0);
    };

    // ---- prologue: stage tile0 fully + B0(1),A0(1); require tile0 resident
    STAGE_B(0, 0); STAGE_A(0, 0); STAGE_A(0, 1); STAGE_B(0, 1);
    STAGE_B(1, 0); STAGE_A(1, 0);
    asm volatile("s_waitcnt vmcnt(4)" ::: "memory");
    BAR();

#pragma unroll 1
    for (int i = 0; i < GKT / 2; ++i) {
        const int u = 2 * i;           // even tile -> buf0
        const int v = 2 * i + 1;       // odd tile  -> buf1
        // ---- P1: tile u, Q(0,0)
        READ_A(0, 0); READ_B(0, 0);
        STAGE_A(v, 1);                         // A1(v): A(v-2) freed last iter P7
        BAR(); LGKM0(); MMQ(0, 0); BAR();
        // ---- P2: Q(0,1)
        READ_B(0, 1);
        STAGE_B(v, 1);                         // B1(v): B(v-2) freed last iter P6
        BAR(); LGKM0(); MMQ(0, 1); BAR();
        // ---- P3: Q(1,0)
        READ_A(0, 1);
        if (u + 2 < GKT) STAGE_B(u + 2, 0);    // B(u) fully read after P2
        BAR(); LGKM0(); MMQ(1, 0); BAR();
        // ---- P4: Q(1,1); check tile v resident
        if (u + 2 < GKT) STAGE_A(u + 2, 0);    // A(u) fully read after P3
        BAR(); MMQ(1, 1);
        if (i < GKT / 2 - 1)
            asm volatile("s_waitcnt vmcnt(4)" ::: "memory");
        else
            asm volatile("s_waitcnt vmcnt(0)" ::: "memory");
        BAR();
        // ---- P5: tile v, Q(0,0)
        READ_A(1, 0); READ_B(1, 0);
        if (u + 2 < GKT) STAGE_A(u + 2, 1);    // A1(u+2): A(u) half1 read done P3
        BAR(); LGKM0(); MMQ(0, 0); BAR();
        // ---- P6: Q(0,1)
        READ_B(1, 1);
        if (u + 2 < GKT) STAGE_B(u + 2, 1);
        BAR(); LGKM0(); MMQ(0, 1); BAR();
        // ---- P7: Q(1,0)
        READ_A(1, 1);
        if (v + 2 < GKT) STAGE_B(v + 2, 0);    // B(v) fully read after P6
        BAR(); LGKM0(); MMQ(1, 0); BAR();
        // ---- P8: Q(1,1); check tile u+2 resident
        if (v + 2 < GKT) STAGE_A(v + 2, 0);    // A(v) fully read after P7
        BAR(); MMQ(1, 1);
        if (i < GKT / 2 - 1) {
            asm volatile("s_waitcnt vmcnt(4)" ::: "memory");
            BAR();
        }
    }

    // epilogue: C/D layout col=lane&15, row=(lane>>4)*4+j  [m89]
#pragma unroll
    for (int mf = 0; mf < 8; ++mf) {
#pragma unroll
        for (int nf = 0; nf < 4; ++nf) {
#pragma unroll
            for (int j = 0; j < 4; ++j) {
                int row = wm * 128 + mf * 16 + kq * 4 + j;
                int col = wn * 64 + nf * 16 + lrow;
                Cbase[(size_t)row * N_DIM + col] = acc[mf][nf][j];
            }
        }
    }
}

// ---------------- Fallback: round-1 fused kernel ----------------
#define BM 128
#define BN 128
#define BK 64
#define KT (K_DIM / BK)

__device__ __forceinline__ int swz_f(int row, int kelem) {
    return kelem ^ (((row ^ (row >> 3)) & 7) << 3);
}

__global__ __launch_bounds__(256) void grouped_gemm_fused_kernel(
    const float* __restrict__ A, const float* __restrict__ W, float* __restrict__ C)
{
    const int bn = blockIdx.x;
    const int bm = blockIdx.y;
    const int e  = blockIdx.z;
    const int tid  = threadIdx.x;
    const int lane = tid & 63;
    const int wid  = tid >> 6;
    const int wr   = wid >> 1;
    const int wc   = wid & 1;

    __shared__ __align__(16) unsigned short fA[BM * BK];
    __shared__ __align__(16) unsigned short fB[BN * BK];

    const float* Abase = A + ((size_t)e * M_PER_E + (size_t)bm * BM) * K_DIM;
    const float* Wbase = W + (size_t)e * K_DIM * N_DIM + (size_t)bn * BN;
    float*       Cbase = C + ((size_t)e * M_PER_E + (size_t)bm * BM) * N_DIM + (size_t)bn * BN;

    const int arow  = tid >> 4;
    const int acol4 = (tid & 15) * 4;
    const int bkq   = tid >> 4;
    const int bnq   = tid & 15;

    f32x4 acc[4][4];
#pragma unroll
    for (int m = 0; m < 4; ++m)
#pragma unroll
        for (int n = 0; n < 4; ++n) acc[m][n] = (f32x4)0.0f;

    float4v ra[8], rb[8];

    auto LOADT = [&](int kt) {
        const float* ap = Abase + (size_t)arow * K_DIM + kt * BK + acol4;
#pragma unroll
        for (int i = 0; i < 8; ++i)
            ra[i] = *reinterpret_cast<const float4v*>(ap + (size_t)i * 16 * K_DIM);
        const float* bp = Wbase + (size_t)(kt * BK + bkq * 4) * N_DIM + bnq * 4;
#pragma unroll
        for (int i = 0; i < 2; ++i)
#pragma unroll
            for (int r = 0; r < 4; ++r)
                rb[i * 4 + r] = *reinterpret_cast<const float4v*>(bp + (size_t)r * N_DIM + i * 64);
    };

    auto STORET = [&]() {
#pragma unroll
        for (int i = 0; i < 8; ++i) {
            int row = arow + i * 16;
            ushort4v v = cvt4_bf16(ra[i]);
            *reinterpret_cast<ushort4v*>(&fA[row * BK + swz_f(row, acol4)]) = v;
        }
#pragma unroll
        for (int i = 0; i < 2; ++i) {
#pragma unroll
            for (int j = 0; j < 4; ++j) {
                int n = (bnq + i * 16) * 4 + j;
                float4v col;
                col[0] = rb[i * 4 + 0][j];
                col[1] = rb[i * 4 + 1][j];
                col[2] = rb[i * 4 + 2][j];
                col[3] = rb[i * 4 + 3][j];
                ushort4v v = cvt4_bf16(col);
                *reinterpret_cast<ushort4v*>(&fB[n * BK + swz_f(n, bkq * 4)]) = v;
            }
        }
    };

    auto COMPUTE = [&]() {
#pragma unroll
        for (int s = 0; s < 2; ++s) {
            bf16x8 af[4], bfr[4];
            const int ke = s * 32 + (lane >> 4) * 8;
#pragma unroll
            for (int m = 0; m < 4; ++m) {
                int row = wr * 64 + m * 16 + (lane & 15);
                af[m] = *reinterpret_cast<const bf16x8*>(&fA[row * BK + swz_f(row, ke)]);
            }
#pragma unroll
            for (int n = 0; n < 4; ++n) {
                int row = wc * 64 + n * 16 + (lane & 15);
                bfr[n] = *reinterpret_cast<const bf16x8*>(&fB[row * BK + swz_f(row, ke)]);
            }
#pragma unroll
            for (int m = 0; m < 4; ++m)
#pragma unroll
                for (int n = 0; n < 4; ++n)
                    acc[m][n] = __builtin_amdgcn_mfma_f32_16x16x32_bf16(
                        af[m], bfr[n], acc[m][n], 0, 0, 0);
        }
    };

    LOADT(0);
    STORET();
    __syncthreads();
    for (int kt = 0; kt < KT; ++kt) {
        if (kt + 1 < KT) LOADT(kt + 1);
        COMPUTE();
        __syncthreads();
        if (kt + 1 < KT) STORET();
        __syncthreads();
    }

#pragma unroll
    for (int m = 0; m < 4; ++m)
#pragma unroll
        for (int n = 0; n < 4; ++n)
#pragma unroll
            for (int j = 0; j < 4; ++j) {
                int row = wr * 64 + m * 16 + (lane >> 4) * 4 + j;
                int col = wc * 64 + n * 16 + (lane & 15);
                Cbase[(size_t)row * N_DIM + col] = acc[m][n][j];
            }
}

extern "C" void kernel_launch(void* const* d_in, const int* in_sizes, int n_in,
                              void* d_out, int out_size, void* d_ws, size_t ws_size,
                              hipStream_t stream) {
    const float* A = (const float*)d_in[0];
    // d_in[1] = expert_size (static 2048 each) — unused
    const float* W = (const float*)d_in[2];
    float* out = (float*)d_out;

    if (ws_size >= WS_NEEDED) {
        unsigned short* wsA = (unsigned short*)d_ws;
        unsigned short* wsW = wsA + (size_t)A_ELEMS;

        hipLaunchKernelGGL(convertA_kernel, dim3(2048), dim3(256), 0, stream,
                           A, wsA, A_ELEMS / 8);
        hipLaunchKernelGGL(transposeW_kernel, dim3(N_DIM / 64, K_DIM / 64, E_NUM),
                           dim3(256), 0, stream, W, wsW);
        hipLaunchKernelGGL(gemm_bf16_kernel, dim3(2048), dim3(512), 0, stream,
                           wsA, wsW, out);
    } else {
        dim3 grid(N_DIM / BN, M_PER_E / BM, E_NUM);
        hipLaunchKernelGGL(grouped_gemm_fused_kernel, grid, dim3(256), 0, stream,
                           A, W, out);
    }
}

// Round 11
// 458.927 us; speedup vs baseline: 2.2020x; 1.0107x over previous
//
#include <hip/hip_runtime.h>
#include <hip/hip_bf16.h>

// Grouped GEMM: E=16 experts, each [2048x1024] @ [1024x4096], fp32 in/out.
// Round 11 = Round 10 GEMM (byte-identical, proven 351 us) + fused prepass
// (single launch, proven in R6-R8):
//   Pass 1 (fused): blocks [0,16384) = W [K][N]->WT [N][K] bf16 transpose;
//                   blocks [16384,18432) = A fp32->bf16 convert.
//   Pass 2 : 256x256 tile, BK=64, 8 waves (2Mx4N), 128 KiB LDS double buffer,
//            full 8-phase schedule (T3+T4), counted vmcnt(4) at P4/P8 only,
//            involution LDS swizzle (conflict-free), setprio (T5),
//            XCD-bijective block swizzle (T1).
// History: R4 reg-tile neutral; R6/R8 counted-waitcnt restructures -> HBM-
// locality collapse; R7 small-tile occupancy -> LDS-bound; R9 conflict-fix ->
// conflicts not critical path. This schedule is the family optimum for this
// shape (m248: 848 TF cap on grouped 256^2 K=1024).

#define E_NUM 16
#define M_PER_E 2048
#define K_DIM 1024
#define N_DIM 4096

#define A_ELEMS (E_NUM * M_PER_E * K_DIM)
#define W_ELEMS (E_NUM * K_DIM * N_DIM)
#define WS_NEEDED ((size_t)A_ELEMS * 2 + (size_t)W_ELEMS * 2)

typedef float  float4v  __attribute__((ext_vector_type(4)));
typedef float  f32x4    __attribute__((ext_vector_type(4)));
typedef short  bf16x8   __attribute__((ext_vector_type(8)));
typedef unsigned short ushort4v __attribute__((ext_vector_type(4)));
typedef unsigned short ushort8v __attribute__((ext_vector_type(8)));

__device__ __forceinline__ ushort4v cvt4_bf16(float4v f) {
    union { __bf16 h[4]; ushort4v u; } x;
#pragma unroll
    for (int j = 0; j < 4; ++j) x.h[j] = (__bf16)f[j];
    return x.u;
}

// ---------------- Pass 1: fused prepass (one launch) ----------------
// blocks [0,16384): W transpose (64x64 tiles); blocks [16384,18432): A convert.
__global__ __launch_bounds__(256) void prepass_kernel(
    const float* __restrict__ A, const float* __restrict__ W,
    unsigned short* __restrict__ outA, unsigned short* __restrict__ outW)
{
    __shared__ __align__(16) float T[64 * 64];
    const int b = blockIdx.x;
    const int t = threadIdx.x;

    if (b < 16384) {
        const int nt = b & 63;
        const int kt = (b >> 6) & 15;
        const int e  = b >> 10;
        const float* Wb = W + ((size_t)e * K_DIM + (size_t)kt * 64) * N_DIM + nt * 64;

#pragma unroll
        for (int j = 0; j < 4; ++j) {
            int kl = (t >> 4) + j * 16;
            int n4 = t & 15;
            float4v v = *reinterpret_cast<const float4v*>(Wb + (size_t)kl * N_DIM + n4 * 4);
            int sp = n4 ^ ((kl >> 3) & 7);
            *reinterpret_cast<float4v*>(&T[kl * 64 + sp * 4]) = v;
        }
        __syncthreads();

#pragma unroll
        for (int c = 0; c < 2; ++c) {
            int nl = (t >> 3) + c * 32;
            int kc = t & 7;
            ushort8v v;
#pragma unroll
            for (int j = 0; j < 8; ++j) {
                int kl = kc * 8 + j;
                int sp = (nl >> 2) ^ kc;           // (kl>>3)&7 == kc here
                float f = T[kl * 64 + sp * 4 + (nl & 3)];
                union { __bf16 h; unsigned short u; } cv; cv.h = (__bf16)f;
                v[j] = cv.u;
            }
            unsigned short* dst = outW + ((size_t)e * N_DIM + (size_t)nt * 64 + nl) * K_DIM
                                  + (size_t)kt * 64 + kc * 8;
            *reinterpret_cast<ushort8v*>(dst) = v;
        }
    } else {
        const int n8 = A_ELEMS / 8;
        int idx = (b - 16384) * 256 + t;
        int stride = 2048 * 256;
        for (int i = idx; i < n8; i += stride) {
            float4v a = *reinterpret_cast<const float4v*>(A + (size_t)i * 8);
            float4v bb = *reinterpret_cast<const float4v*>(A + (size_t)i * 8 + 4);
            ushort8v v;
            ushort4v va = cvt4_bf16(a), vb = cvt4_bf16(bb);
#pragma unroll
            for (int j = 0; j < 4; ++j) { v[j] = va[j]; v[j + 4] = vb[j]; }
            *reinterpret_cast<ushort8v*>(outA + (size_t)i * 8) = v;
        }
    }
}

// ---------------- Pass 2: 256^2 bf16 GEMM, 8-phase pipeline ------------------
#define GBM 256
#define GBN 256
#define GBK 64
#define GKT (K_DIM / GBK)   // 16 K-tiles, 8 iters of 2

#define BAR()   __builtin_amdgcn_s_barrier()
#define LGKM0() asm volatile("s_waitcnt lgkmcnt(0)" ::: "memory")

__global__ __launch_bounds__(512, 2) void gemm_bf16_kernel(
    const unsigned short* __restrict__ A,   // [E*2048][1024] bf16
    const unsigned short* __restrict__ B,   // [E*4096][1024] bf16 (W^T)
    float* __restrict__ C)                  // [E*2048][4096] fp32
{
    // XCD-bijective swizzle over 2048 blocks (2048 % 8 == 0)
    const int bid = blockIdx.x;
    const int swzid = (bid & 7) * (2048 / 8) + (bid >> 3);
    const int e   = swzid >> 7;        // 128 tiles/expert
    const int rem = swzid & 127;
    const int bm  = rem >> 4;          // 0..7
    const int bn  = rem & 15;          // 0..15

    const int tid  = threadIdx.x;
    const int lane = tid & 63;
    const int wid  = tid >> 6;         // 0..7
    const int wm   = wid >> 2;         // 0..1  (128 rows)
    const int wn   = wid & 3;          // 0..3  (64 cols)
    const int lrow = lane & 15;
    const int kq   = lane >> 4;        // 0..3

    // 128 KiB: 2 bufs x (A 32KB + B 32KB); halves = 128 rows each
    __shared__ __align__(16) unsigned short sA[2][GBM * GBK];
    __shared__ __align__(16) unsigned short sB[2][GBN * GBK];

    const unsigned short* Abase = A + ((size_t)e * M_PER_E + (size_t)bm * GBM) * K_DIM;
    const unsigned short* Bbase = B + ((size_t)e * N_DIM  + (size_t)bn * GBN) * K_DIM;
    float*                Cbase = C + ((size_t)e * M_PER_E + (size_t)bm * GBM) * N_DIM
                                    + (size_t)bn * GBN;

    // Involution swizzle: LDS row = 128B = 8 slots of 16B.
    // phys_slot = logical_chunk ^ (row & 7); gload_lds writes linearly, so the
    // global source pre-applies the inverse.
    const int schunk = (lane & 7) ^ ((lane >> 3) & 7);
    const int srow   = lane >> 3;

    // stage one half-tile (128 rows x 64 k) of A or B: 2 gload_lds per thread
    auto STAGE_A = [&](int t, int h) {
        const unsigned short* g = Abase + (size_t)t * GBK + schunk * 8;
#pragma unroll
        for (int j = 0; j < 2; ++j) {
            const int rb = h * 128 + (wid * 2 + j) * 8;
            __builtin_amdgcn_global_load_lds(
                (const __attribute__((address_space(1))) void*)(g + (size_t)(rb + srow) * K_DIM),
                (__attribute__((address_space(3))) void*)&sA[t & 1][rb * GBK], 16, 0, 0);
        }
    };
    auto STAGE_B = [&](int t, int h) {
        const unsigned short* g = Bbase + (size_t)t * GBK + schunk * 8;
#pragma unroll
        for (int j = 0; j < 2; ++j) {
            const int rb = h * 128 + (wid * 2 + j) * 8;
            __builtin_amdgcn_global_load_lds(
                (const __attribute__((address_space(1))) void*)(g + (size_t)(rb + srow) * K_DIM),
                (__attribute__((address_space(3))) void*)&sB[t & 1][rb * GBK], 16, 0, 0);
        }
    };

    f32x4 acc[8][4];
#pragma unroll
    for (int mf = 0; mf < 8; ++mf)
#pragma unroll
        for (int nf = 0; nf < 4; ++nf) acc[mf][nf] = (f32x4)0.0f;

    bf16x8 af[4][2];   // current A quadrant (4 m-frags x 2 k-slices)
    bf16x8 bf[4][2];   // full B panel (4 n-frags x 2 k-slices)

    auto READ_A = [&](int p, int mh) {   // af <- A-half quadrant mh
#pragma unroll
        for (int s = 0; s < 2; ++s) {
            const int slot = (s * 4 + kq) ^ (lrow & 7);
#pragma unroll
            for (int mf = 0; mf < 4; ++mf) {
                int row = wm * 128 + mh * 64 + mf * 16 + lrow;
                af[mf][s] = *reinterpret_cast<const bf16x8*>(&sA[p][row * GBK + slot * 8]);
            }
        }
    };
    auto READ_B = [&](int p, int bh) {   // bf[bh*2..+1]
#pragma unroll
        for (int s = 0; s < 2; ++s) {
            const int slot = (s * 4 + kq) ^ (lrow & 7);
#pragma unroll
            for (int nf = 0; nf < 2; ++nf) {
                int row = wn * 64 + (bh * 2 + nf) * 16 + lrow;
                bf[bh * 2 + nf][s] = *reinterpret_cast<const bf16x8*>(&sB[p][row * GBK + slot * 8]);
            }
        }
    };

    auto MMQ = [&](int mh, int nh) {     // 16 MFMA, one C-quadrant slice
        __builtin_amdgcn_s_setprio(1);
#pragma unroll
        for (int s = 0; s < 2; ++s)
#pragma unroll
            for (int nf = nh * 2; nf < nh * 2 + 2; ++nf)
#pragma unroll
                for (int mf = 0; mf < 4; ++mf)
                    acc[mh * 4 + mf][nf] = __builtin_amdgcn_mfma_f32_16x16x32_bf16(
                        af[mf][s], bf[nf][s], acc[mh * 4 + mf][nf], 0, 0, 0);
        __builtin_amdgcn_s_setprio(0);
    };

    // ---- prologue: stage tile0 fully + B0(1),A0(1); require tile0 resident
    STAGE_B(0, 0); STAGE_A(0, 0); STAGE_A(0, 1); STAGE_B(0, 1);
    STAGE_B(1, 0); STAGE_A(1, 0);
    asm volatile("s_waitcnt vmcnt(4)" ::: "memory");
    BAR();

#pragma unroll 1
    for (int i = 0; i < GKT / 2; ++i) {
        const int u = 2 * i;           // even tile -> buf0
        const int v = 2 * i + 1;       // odd tile  -> buf1
        // ---- P1: tile u, Q(0,0)
        READ_A(0, 0); READ_B(0, 0);
        STAGE_A(v, 1);                         // A1(v): A(v-2) freed last iter P7
        BAR(); LGKM0(); MMQ(0, 0); BAR();
        // ---- P2: Q(0,1)
        READ_B(0, 1);
        STAGE_B(v, 1);                         // B1(v): B(v-2) freed last iter P6
        BAR(); LGKM0(); MMQ(0, 1); BAR();
        // ---- P3: Q(1,0)
        READ_A(0, 1);
        if (u + 2 < GKT) STAGE_B(u + 2, 0);    // B(u) fully read after P2
        BAR(); LGKM0(); MMQ(1, 0); BAR();
        // ---- P4: Q(1,1); check tile v resident
        if (u + 2 < GKT) STAGE_A(u + 2, 0);    // A(u) fully read after P3
        BAR(); MMQ(1, 1);
        if (i < GKT / 2 - 1)
            asm volatile("s_waitcnt vmcnt(4)" ::: "memory");
        else
            asm volatile("s_waitcnt vmcnt(0)" ::: "memory");
        BAR();
        // ---- P5: tile v, Q(0,0)
        READ_A(1, 0); READ_B(1, 0);
        if (u + 2 < GKT) STAGE_A(u + 2, 1);    // A1(u+2): A(u) half1 read done P3
        BAR(); LGKM0(); MMQ(0, 0); BAR();
        // ---- P6: Q(0,1)
        READ_B(1, 1);
        if (u + 2 < GKT) STAGE_B(u + 2, 1);
        BAR(); LGKM0(); MMQ(0, 1); BAR();
        // ---- P7: Q(1,0)
        READ_A(1, 1);
        if (v + 2 < GKT) STAGE_B(v + 2, 0);    // B(v) fully read after P6
        BAR(); LGKM0(); MMQ(1, 0); BAR();
        // ---- P8: Q(1,1); check tile u+2 resident
        if (v + 2 < GKT) STAGE_A(v + 2, 0);    // A(v) fully read after P7
        BAR(); MMQ(1, 1);
        if (i < GKT / 2 - 1) {
            asm volatile("s_waitcnt vmcnt(4)" ::: "memory");
            BAR();
        }
    }

    // epilogue: C/D layout col=lane&15, row=(lane>>4)*4+j  [m89]
#pragma unroll
    for (int mf = 0; mf < 8; ++mf) {
#pragma unroll
        for (int nf = 0; nf < 4; ++nf) {
#pragma unroll
            for (int j = 0; j < 4; ++j) {
                int row = wm * 128 + mf * 16 + kq * 4 + j;
                int col = wn * 64 + nf * 16 + lrow;
                Cbase[(size_t)row * N_DIM + col] = acc[mf][nf][j];
            }
        }
    }
}

// ---------------- Fallback: round-1 fused kernel ----------------
#define BM 128
#define BN 128
#define BK 64
#define KT (K_DIM / BK)

__device__ __forceinline__ int swz_f(int row, int kelem) {
    return kelem ^ (((row ^ (row >> 3)) & 7) << 3);
}

__global__ __launch_bounds__(256) void grouped_gemm_fused_kernel(
    const float* __restrict__ A, const float* __restrict__ W, float* __restrict__ C)
{
    const int bn = blockIdx.x;
    const int bm = blockIdx.y;
    const int e  = blockIdx.z;
    const int tid  = threadIdx.x;
    const int lane = tid & 63;
    const int wid  = tid >> 6;
    const int wr   = wid >> 1;
    const int wc   = wid & 1;

    __shared__ __align__(16) unsigned short fA[BM * BK];
    __shared__ __align__(16) unsigned short fB[BN * BK];

    const float* Abase = A + ((size_t)e * M_PER_E + (size_t)bm * BM) * K_DIM;
    const float* Wbase = W + (size_t)e * K_DIM * N_DIM + (size_t)bn * BN;
    float*       Cbase = C + ((size_t)e * M_PER_E + (size_t)bm * BM) * N_DIM + (size_t)bn * BN;

    const int arow  = tid >> 4;
    const int acol4 = (tid & 15) * 4;
    const int bkq   = tid >> 4;
    const int bnq   = tid & 15;

    f32x4 acc[4][4];
#pragma unroll
    for (int m = 0; m < 4; ++m)
#pragma unroll
        for (int n = 0; n < 4; ++n) acc[m][n] = (f32x4)0.0f;

    float4v ra[8], rb[8];

    auto LOADT = [&](int kt) {
        const float* ap = Abase + (size_t)arow * K_DIM + kt * BK + acol4;
#pragma unroll
        for (int i = 0; i < 8; ++i)
            ra[i] = *reinterpret_cast<const float4v*>(ap + (size_t)i * 16 * K_DIM);
        const float* bp = Wbase + (size_t)(kt * BK + bkq * 4) * N_DIM + bnq * 4;
#pragma unroll
        for (int i = 0; i < 2; ++i)
#pragma unroll
            for (int r = 0; r < 4; ++r)
                rb[i * 4 + r] = *reinterpret_cast<const float4v*>(bp + (size_t)r * N_DIM + i * 64);
    };

    auto STORET = [&]() {
#pragma unroll
        for (int i = 0; i < 8; ++i) {
            int row = arow + i * 16;
            ushort4v v = cvt4_bf16(ra[i]);
            *reinterpret_cast<ushort4v*>(&fA[row * BK + swz_f(row, acol4)]) = v;
        }
#pragma unroll
        for (int i = 0; i < 2; ++i) {
#pragma unroll
            for (int j = 0; j < 4; ++j) {
                int n = (bnq + i * 16) * 4 + j;
                float4v col;
                col[0] = rb[i * 4 + 0][j];
                col[1] = rb[i * 4 + 1][j];
                col[2] = rb[i * 4 + 2][j];
                col[3] = rb[i * 4 + 3][j];
                ushort4v v = cvt4_bf16(col);
                *reinterpret_cast<ushort4v*>(&fB[n * BK + swz_f(n, bkq * 4)]) = v;
            }
        }
    };

    auto COMPUTE = [&]() {
#pragma unroll
        for (int s = 0; s < 2; ++s) {
            bf16x8 af[4], bfr[4];
            const int ke = s * 32 + (lane >> 4) * 8;
#pragma unroll
            for (int m = 0; m < 4; ++m) {
                int row = wr * 64 + m * 16 + (lane & 15);
                af[m] = *reinterpret_cast<const bf16x8*>(&fA[row * BK + swz_f(row, ke)]);
            }
#pragma unroll
            for (int n = 0; n < 4; ++n) {
                int row = wc * 64 + n * 16 + (lane & 15);
                bfr[n] = *reinterpret_cast<const bf16x8*>(&fB[row * BK + swz_f(row, ke)]);
            }
#pragma unroll
            for (int m = 0; m < 4; ++m)
#pragma unroll
                for (int n = 0; n < 4; ++n)
                    acc[m][n] = __builtin_amdgcn_mfma_f32_16x16x32_bf16(
                        af[m], bfr[n], acc[m][n], 0, 0, 0);
        }
    };

    LOADT(0);
    STORET();
    __syncthreads();
    for (int kt = 0; kt < KT; ++kt) {
        if (kt + 1 < KT) LOADT(kt + 1);
        COMPUTE();
        __syncthreads();
        if (kt + 1 < KT) STORET();
        __syncthreads();
    }

#pragma unroll
    for (int m = 0; m < 4; ++m)
#pragma unroll
        for (int n = 0; n < 4; ++n)
#pragma unroll
            for (int j = 0; j < 4; ++j) {
                int row = wr * 64 + m * 16 + (lane >> 4) * 4 + j;
                int col = wc * 64 + n * 16 + (lane & 15);
                Cbase[(size_t)row * N_DIM + col] = acc[m][n][j];
            }
}

extern "C" void kernel_launch(void* const* d_in, const int* in_sizes, int n_in,
                              void* d_out, int out_size, void* d_ws, size_t ws_size,
                              hipStream_t stream) {
    const float* A = (const float*)d_in[0];
    // d_in[1] = expert_size (static 2048 each) — unused
    const float* W = (const float*)d_in[2];
    float* out = (float*)d_out;

    if (ws_size >= WS_NEEDED) {
        unsigned short* wsA = (unsigned short*)d_ws;
        unsigned short* wsW = wsA + (size_t)A_ELEMS;

        hipLaunchKernelGGL(prepass_kernel, dim3(18432), dim3(256), 0, stream,
                           A, W, wsA, wsW);
        hipLaunchKernelGGL(gemm_bf16_kernel, dim3(2048), dim3(512), 0, stream,
                           wsA, wsW, out);
    } else {
        dim3 grid(N_DIM / BN, M_PER_E / BM, E_NUM);
        hipLaunchKernelGGL(grouped_gemm_fused_kernel, grid, dim3(256), 0, stream,
                           A, W, out);
    }
}